// Round 4
// baseline (466.031 us; speedup 1.0000x reference)
//
#include <hip/hip_runtime.h>
#include <hip/hip_bf16.h>

#define NN 10000
#define NE 320000
#define HD 128
#define TILE 128
#define NTILES (NE / TILE)   // 2500 exactly

typedef __attribute__((ext_vector_type(8))) short s16x8;
typedef __attribute__((ext_vector_type(4))) short s16x4;
typedef __attribute__((ext_vector_type(4))) float f32x4;

__device__ __forceinline__ short f2bf(float f) {
    union { float f; unsigned u; } v; v.f = f;
    unsigned r = v.u + 0x7FFFu + ((v.u >> 16) & 1u);   // RNE
    return (short)(r >> 16);
}
__device__ __forceinline__ float bf2f(short s) {
    union { unsigned u; float f; } v;
    v.u = ((unsigned)(unsigned short)s) << 16;
    return v.f;
}

// ---------------- CSR build (edges sorted by dst) + fused weight prep ----------------
struct WPtrs { const float* w[8]; };

__global__ void hist_kernel(const int* __restrict__ dst, int* __restrict__ cnt,
                            WPtrs p, ushort* __restrict__ wdst) {
    int e = blockIdx.x * blockDim.x + threadIdx.x;
    if (e < NE) atomicAdd(&cnt[dst[e]], 1);
    int tid = e;
    int m, idx;
    if (tid < 7 * 16384) { m = tid >> 14; idx = tid & 16383; }
    else if (tid < 7 * 16384 + 2048) { m = 7; idx = tid - 7 * 16384; }
    else return;
    int b = m >> 1, l = m & 1;
    int C = (m == 7) ? 16 : 128;
    int k = idx / C, c = idx % C;
    float v = p.w[m][k * C + c];
    wdst[l * 65536 + b * 16384 + c * 128 + k] = (ushort)f2bf(v);
}

__global__ void scan_kernel(const int* __restrict__ cnt, int* __restrict__ rs, int* __restrict__ cur) {
    __shared__ int part[256];
    int t = threadIdx.x;
    const int CH = (NN + 255) / 256;  // 40
    int base = t * CH;
    int s = 0;
    for (int i = 0; i < CH; i++) {
        int idx = base + i;
        if (idx < NN) s += cnt[idx];
    }
    part[t] = s;
    __syncthreads();
    for (int off = 1; off < 256; off <<= 1) {
        int v = (t >= off) ? part[t - off] : 0;
        __syncthreads();
        part[t] += v;
        __syncthreads();
    }
    int run = part[t] - s;
    for (int i = 0; i < CH; i++) {
        int idx = base + i;
        if (idx < NN) {
            rs[idx] = run;
            cur[idx] = run;
            run += cnt[idx];
        }
    }
    if (t == 255) rs[NN] = run;
}

__global__ void scatter_kernel(const int* __restrict__ src, const int* __restrict__ dst,
                               int* __restrict__ cur, int* __restrict__ ssrc) {
    int e = blockIdx.x * blockDim.x + threadIdx.x;
    if (e < NE) {
        int p = atomicAdd(&cur[dst[e]], 1);
        ssrc[p] = src[e];
    }
}

__global__ void nodeof_kernel(const int* __restrict__ rs, int* __restrict__ nof) {
    int n = blockIdx.x * blockDim.x + threadIdx.x;
    if (n < NN) {
        int b = rs[n], e = rs[n + 1];
        for (int s = b; s < e; s++) nof[s] = n;
    }
}

// ---------------- per-node layer-1 factorization -> bf16 A/B, fused zero-fill ----------------
template<int D, int ZD>
__global__ __launch_bounds__(256)
void nodeAB_kernel(const float* __restrict__ x, const float* __restrict__ W0,
                   const float* __restrict__ b0, ushort* __restrict__ A,
                   ushort* __restrict__ Bm, float* __restrict__ zbuf) {
    __shared__ float xs[8 * 128];
    int t = threadIdx.x;
    int n0 = blockIdx.x * 8;
    for (int i = t; i < 8 * D; i += 256) {
        int n = i / D, d = i % D;
        xs[n * 128 + d] = x[(size_t)(n0 + n) * D + d];
    }
    for (int i = t; i < 8 * ZD; i += 256) zbuf[(size_t)n0 * ZD + i] = 0.f;
    __syncthreads();
    int c = t & 127;
    int h = t >> 7;
    float a[4], b[4];
    float bias = b0[c];
#pragma unroll
    for (int n = 0; n < 4; n++) { a[n] = bias; b[n] = 0.f; }
    for (int d = 0; d < D; d++) {
        float wt = W0[d * HD + c];
        float wb = W0[(D + d) * HD + c];
        float wd = wt - wb;
#pragma unroll
        for (int n = 0; n < 4; n++) {
            float xv = xs[(h * 4 + n) * 128 + d];
            a[n] += xv * wd;
            b[n] += xv * wb;
        }
    }
#pragma unroll
    for (int n = 0; n < 4; n++) {
        int gn = n0 + h * 4 + n;
        A[(size_t)gn * HD + c] = (ushort)f2bf(a[n]);
        Bm[(size_t)gn * HD + c] = (ushort)f2bf(b[n]);
    }
}

// ---------------- persistent MFMA edge kernel ----------------
// Weights held in VGPRs for the whole block lifetime; A-rows staged by distinct
// dst range; aggregation via rs[] with plain stores for unclipped segments.
// C/D frag: col(e) = lane&15, row(c) = (lane>>4)*4 + reg   [m89/m91 verified]
template<int DOUTB>
__global__ __launch_bounds__(256, 2)
void edge_mfma_kernel(const ushort* __restrict__ Af, const ushort* __restrict__ Bf,
                      const ushort* __restrict__ W1T, const float* __restrict__ b1,
                      const ushort* __restrict__ W2T, const float* __restrict__ b2,
                      const int* __restrict__ ssrc, const int* __restrict__ nof,
                      const int* __restrict__ rs, float* __restrict__ out) {
    __shared__ __align__(16) ushort HH[128 * 136];    // 34816 B: h1 -> h2 -> MS f32[64][132]
    __shared__ __align__(16) ushort ALDS[32 * 136];   // 8704 B: staged A rows
    __shared__ int s_node[TILE];
    __shared__ int s_src[TILE];

    const int t = threadIdx.x;
    const int lane = t & 63;
    const int w = t >> 6;
    const int lr = lane & 15;
    const int lg = lane >> 4;
    const int wr = w >> 1;      // layer-2 c-block (64)
    const int wc = w & 1;       // layer-2 e-block (64)

    constexpr int MT3 = (DOUTB == 128) ? 4 : 1;
    constexpr int NT3 = (DOUTB == 128) ? 4 : 2;
    const int cBase3 = (DOUTB == 128) ? wr * 64 : 0;
    const int eBase3 = (DOUTB == 128) ? wc * 64 : w * 32;

    // ---- persistent weight fragments in VGPRs ----
    s16x8 w1f[4][4];   // [m][ks]
#pragma unroll
    for (int m = 0; m < 4; m++)
#pragma unroll
        for (int ks = 0; ks < 4; ks++)
            w1f[m][ks] = *(const s16x8*)(W1T + (size_t)(wr * 64 + m * 16 + lr) * HD + ks * 32 + lg * 8);
    s16x8 w2f[MT3][4];
#pragma unroll
    for (int m = 0; m < MT3; m++)
#pragma unroll
        for (int ks = 0; ks < 4; ks++)
            w2f[m][ks] = *(const s16x8*)(W2T + (size_t)(cBase3 + m * 16 + lr) * HD + ks * 32 + lg * 8);

    float bias2[4][4];
#pragma unroll
    for (int m = 0; m < 4; m++)
#pragma unroll
        for (int r = 0; r < 4; r++)
            bias2[m][r] = b1[wr * 64 + m * 16 + lg * 4 + r];
    float bias3[MT3][4];
#pragma unroll
    for (int m = 0; m < MT3; m++)
#pragma unroll
        for (int r = 0; r < 4; r++)
            bias3[m][r] = b2[cBase3 + m * 16 + lg * 4 + r];

    for (int tile = blockIdx.x; tile < NTILES; tile += gridDim.x) {
        const int ts = tile * TILE;
        __syncthreads();   // prev iteration fully consumed
        if (t < TILE) { s_node[t] = nof[ts + t]; s_src[t] = ssrc[ts + t]; }
        __syncthreads();

        // ---- h1 fill: HH[e][k] = bf16(relu(A[dst][k] + B[src][k])) ----
        const int nd0 = s_node[0];
        const int rng = s_node[TILE - 1] - nd0 + 1;
        if (rng <= 32) {
            // stage distinct A rows once (dst sorted -> tiny range)
            for (int i = t; i < rng * 16; i += 256) {
                const int r = i >> 4, cg = i & 15;
                *(s16x8*)(ALDS + r * 136 + cg * 8) =
                    *(const s16x8*)(Af + (size_t)(nd0 + r) * HD + cg * 8);
            }
            __syncthreads();
            for (int i = t; i < TILE * 16; i += 256) {
                const int e = i >> 4, cg = i & 15;
                const s16x8 av = *(const s16x8*)(ALDS + (s_node[e] - nd0) * 136 + cg * 8);
                const s16x8 bv = *(const s16x8*)(Bf + (size_t)s_src[e] * HD + cg * 8);
                s16x8 hv;
#pragma unroll
                for (int j = 0; j < 8; j++)
                    hv[j] = f2bf(fmaxf(bf2f(av[j]) + bf2f(bv[j]), 0.f));
                *(s16x8*)(HH + e * 136 + cg * 8) = hv;
            }
        } else {
            // fallback: direct gather (pathological dst distribution)
            for (int i = t; i < TILE * 16; i += 256) {
                const int e = i >> 4, cg = i & 15;
                const s16x8 av = *(const s16x8*)(Af + (size_t)s_node[e] * HD + cg * 8);
                const s16x8 bv = *(const s16x8*)(Bf + (size_t)s_src[e] * HD + cg * 8);
                s16x8 hv;
#pragma unroll
                for (int j = 0; j < 8; j++)
                    hv[j] = f2bf(fmaxf(bf2f(av[j]) + bf2f(bv[j]), 0.f));
                *(s16x8*)(HH + e * 136 + cg * 8) = hv;
            }
        }
        __syncthreads();

        // ---- layer 2: c[wr*64,+64) x e[wc*64,+64) ----
        f32x4 acc[4][4];
#pragma unroll
        for (int m = 0; m < 4; m++)
#pragma unroll
            for (int n = 0; n < 4; n++) {
                f32x4 v; v[0] = bias2[m][0]; v[1] = bias2[m][1]; v[2] = bias2[m][2]; v[3] = bias2[m][3];
                acc[m][n] = v;
            }
#pragma unroll
        for (int ks = 0; ks < 4; ks++) {
            const int k0 = ks * 32 + lg * 8;
            s16x8 bfr[4];
#pragma unroll
            for (int n = 0; n < 4; n++)
                bfr[n] = *(const s16x8*)(HH + (wc * 64 + n * 16 + lr) * 136 + k0);
#pragma unroll
            for (int m = 0; m < 4; m++)
#pragma unroll
                for (int n = 0; n < 4; n++)
                    acc[m][n] = __builtin_amdgcn_mfma_f32_16x16x32_bf16(w1f[m][ks], bfr[n], acc[m][n], 0, 0, 0);
        }
        __syncthreads();   // all h1 reads complete

        // write h2 = relu(acc) in-place: HH[e][c]
#pragma unroll
        for (int m = 0; m < 4; m++)
#pragma unroll
            for (int n = 0; n < 4; n++) {
                const int e = wc * 64 + n * 16 + lr;
                const int c0 = wr * 64 + m * 16 + lg * 4;
                s16x4 hv;
                hv[0] = f2bf(fmaxf(acc[m][n][0], 0.f));
                hv[1] = f2bf(fmaxf(acc[m][n][1], 0.f));
                hv[2] = f2bf(fmaxf(acc[m][n][2], 0.f));
                hv[3] = f2bf(fmaxf(acc[m][n][3], 0.f));
                *(s16x4*)(HH + e * 136 + c0) = hv;
            }
        __syncthreads();

        // ---- layer 3: m[c][e] (no relu) ----
        f32x4 acc2[MT3][NT3];
#pragma unroll
        for (int m = 0; m < MT3; m++)
#pragma unroll
            for (int n = 0; n < NT3; n++) {
                f32x4 v; v[0] = bias3[m][0]; v[1] = bias3[m][1]; v[2] = bias3[m][2]; v[3] = bias3[m][3];
                acc2[m][n] = v;
            }
#pragma unroll
        for (int ks = 0; ks < 4; ks++) {
            const int k0 = ks * 32 + lg * 8;
            s16x8 bfr[NT3];
#pragma unroll
            for (int n = 0; n < NT3; n++)
                bfr[n] = *(const s16x8*)(HH + (eBase3 + n * 16 + lr) * 136 + k0);
#pragma unroll
            for (int m = 0; m < MT3; m++)
#pragma unroll
                for (int n = 0; n < NT3; n++)
                    acc2[m][n] = __builtin_amdgcn_mfma_f32_16x16x32_bf16(w2f[m][ks], bfr[n], acc2[m][n], 0, 0, 0);
        }
        __syncthreads();   // all h2 reads complete -> HH reusable as MS

        // ---- aggregation in two 64-edge halves; rs-exact segments ----
        float* MS = (float*)HH;   // f32 [64][132]
#pragma unroll
        for (int half = 0; half < 2; half++) {
            if ((eBase3 >> 6) == half) {
                const int eloc = eBase3 & 63;
#pragma unroll
                for (int m = 0; m < MT3; m++)
#pragma unroll
                    for (int n = 0; n < NT3; n++)
                        *(f32x4*)(MS + (eloc + n * 16 + lr) * 132 + cBase3 + m * 16 + lg * 4) = acc2[m][n];
            }
            __syncthreads();
            {
                const int s0 = ts + half * 64;
                const int nfirst = s_node[half * 64];
                const int nlast = s_node[half * 64 + 63];
                const int nitems = (nlast - nfirst + 1) * DOUTB;
                for (int idx = t; idx < nitems; idx += 256) {
                    const int n = nfirst + idx / DOUTB;
                    const int c = idx & (DOUTB - 1);
                    const int lo = rs[n], hi = rs[n + 1];
                    const int clo = max(lo, s0), chi = min(hi, s0 + 64);
                    float sum = 0.f;
                    for (int s = clo; s < chi; s++) sum += MS[(s - s0) * 132 + c];
                    float* dp = out + (size_t)n * DOUTB + c;
                    if (lo < s0 || hi > s0 + 64) {
                        if (chi > clo) atomicAdd(dp, sum);
                    } else {
                        *dp = sum;   // segment fully inside this half: single writer
                    }
                }
            }
            __syncthreads();
        }
    }
}

extern "C" void kernel_launch(void* const* d_in, const int* in_sizes, int n_in,
                              void* d_out, int out_size, void* d_ws, size_t ws_size,
                              hipStream_t stream) {
    const float* x = (const float*)d_in[0];
    const int* ei = (const int*)d_in[2];
    const int* src = ei;
    const int* dst = ei + NE;
    const float* W[4][3];
    const float* bs[4][3];
    for (int b = 0; b < 4; b++)
        for (int l = 0; l < 3; l++) {
            W[b][l]  = (const float*)d_in[4 + b * 6 + l * 2];
            bs[b][l] = (const float*)d_in[4 + b * 6 + l * 2 + 1];
        }

    float* x0   = (float*)d_ws;
    float* x1   = x0 + (size_t)NN * HD;
    ushort* A   = (ushort*)(x1 + (size_t)NN * HD);
    ushort* Bm  = A + (size_t)NN * HD;
    ushort* WT  = Bm + (size_t)NN * HD;       // 131072 ushort = 256 KB
    int* cnt    = (int*)(WT + 131072);
    int* rs     = cnt + NN;
    int* cur    = rs + NN + 1;
    int* ssrc   = cur + NN;
    int* nof    = ssrc + NE;
    float* out  = (float*)d_out;

    WPtrs wp;
    for (int b = 0; b < 4; b++) { wp.w[2 * b] = W[b][1]; wp.w[2 * b + 1] = W[b][2]; }
    hipMemsetAsync(cnt, 0, NN * sizeof(int), stream);
    hist_kernel<<<(NE + 255) / 256, 256, 0, stream>>>(dst, cnt, wp, WT);
    scan_kernel<<<1, 256, 0, stream>>>(cnt, rs, cur);
    scatter_kernel<<<(NE + 255) / 256, 256, 0, stream>>>(src, dst, cur, ssrc);
    nodeof_kernel<<<(NN + 255) / 256, 256, 0, stream>>>(rs, nof);

    const ushort* W1T[4];
    const ushort* W2T[4];
    for (int b = 0; b < 4; b++) { W1T[b] = WT + b * 16384; W2T[b] = WT + 65536 + b * 16384; }

    const int EG = 512;   // 2 blocks/CU co-resident, grid-stride over tiles

    // block 0 (nodeAB zeroes x0)
    nodeAB_kernel<4, 128><<<NN / 8, 256, 0, stream>>>(x, W[0][0], bs[0][0], A, Bm, x0);
    edge_mfma_kernel<128><<<EG, 256, 0, stream>>>(A, Bm, W1T[0], bs[0][1], W2T[0], bs[0][2], ssrc, nof, rs, x0);
    // block 1 (zeroes x1)
    nodeAB_kernel<128, 128><<<NN / 8, 256, 0, stream>>>(x0, W[1][0], bs[1][0], A, Bm, x1);
    edge_mfma_kernel<128><<<EG, 256, 0, stream>>>(A, Bm, W1T[1], bs[1][1], W2T[1], bs[1][2], ssrc, nof, rs, x1);
    // block 2 (zeroes x0)
    nodeAB_kernel<128, 128><<<NN / 8, 256, 0, stream>>>(x1, W[2][0], bs[2][0], A, Bm, x0);
    edge_mfma_kernel<128><<<EG, 256, 0, stream>>>(A, Bm, W1T[2], bs[2][1], W2T[2], bs[2][2], ssrc, nof, rs, x0);
    // block 3 (zeroes out) -> d_out
    nodeAB_kernel<128, 16><<<NN / 8, 256, 0, stream>>>(x0, W[3][0], bs[3][0], A, Bm, out);
    edge_mfma_kernel<16><<<EG, 256, 0, stream>>>(A, Bm, W1T[3], bs[3][1], W2T[3], bs[3][2], ssrc, nof, rs, out);
}